// Round 12
// baseline (182.647 us; speedup 1.0000x reference)
//
#include <hip/hip_runtime.h>
#include <hip/hip_bf16.h>

#define NN 8192
#define NE 262144

typedef __attribute__((ext_vector_type(8))) short bf16x8;
typedef __attribute__((ext_vector_type(4))) float f32x4;
typedef __attribute__((ext_vector_type(16))) float f32x16;
typedef unsigned short u16;
typedef __attribute__((ext_vector_type(4))) u16 u16x4;

__device__ inline u16 f2b(float f) {
  unsigned u = __float_as_uint(f);
  unsigned r = u + 0x7FFF + ((u >> 16) & 1);   // RNE to bf16
  return (u16)(r >> 16);
}
__device__ inline float b2f(u16 b) {
  return __uint_as_float(((unsigned)b) << 16);
}

// ---------- fused prep: x->bf16 (4096 blks) | W1^T (512) | W23^T (256) | hist (1024) --
__global__ void prep_kernel(const float* __restrict__ x, const float* __restrict__ W1,
                            const float* __restrict__ W2, const float* __restrict__ W3,
                            const int* __restrict__ dst, int* __restrict__ deg,
                            u16* __restrict__ xb, u16* __restrict__ W1T,
                            u16* __restrict__ W23T) {
  int b = blockIdx.x;
  if (b < 4096) {
    int i = (b * 256 + threadIdx.x) * 4;
    f32x4 v = *(const f32x4*)(x + i);
    u16x4 o;
#pragma unroll
    for (int j = 0; j < 4; ++j) o[j] = f2b(v[j]);
    *(u16x4*)(xb + i) = o;
  } else if (b < 4096 + 512) {
    int i = (b - 4096) * 256 + threadIdx.x;   // 512*256 elems
    int k = i >> 8, n = i & 255;
    W1T[(size_t)n * 512 + k] = f2b(W1[i]);
  } else if (b < 4096 + 512 + 256) {
    int i = (b - 4608) * 256 + threadIdx.x;   // 65536 elems
    int k = i >> 8, j = i & 255;
    float v = (j < 128) ? W2[(k << 7) + j] : W3[(k << 7) + (j - 128)];
    W23T[(size_t)j * 256 + k] = f2b(v);
  } else {
    int i = (b - 4864) * 256 + threadIdx.x;   // NE elems
    if (i < NE) atomicAdd(&deg[dst[i]], 1);
  }
}

// ---------- CSR build ----------
__global__ void scan_kernel(const int* __restrict__ deg, int* __restrict__ rowptr,
                            int* __restrict__ cursor) {
  __shared__ int sums[1024];
  int t = threadIdx.x;
  int loc[8];
  int s = 0;
#pragma unroll
  for (int j = 0; j < 8; ++j) { s += deg[t * 8 + j]; loc[j] = s; }
  sums[t] = s;
  __syncthreads();
  for (int off = 1; off < 1024; off <<= 1) {
    int v = (t >= off) ? sums[t - off] : 0;
    __syncthreads();
    sums[t] += v;
    __syncthreads();
  }
  int base = (t > 0) ? sums[t - 1] : 0;
  if (t == 0) rowptr[0] = 0;
#pragma unroll
  for (int j = 0; j < 8; ++j) {
    rowptr[t * 8 + j + 1] = base + loc[j];
    cursor[t * 8 + j] = base + (j ? loc[j - 1] : 0);
  }
}

__global__ void scatter_kernel(const int* __restrict__ src, const int* __restrict__ dst,
                               const float* __restrict__ w, int* cursor,
                               int* __restrict__ csr_src, float* __restrict__ csr_w) {
  int i = blockIdx.x * blockDim.x + threadIdx.x;
  if (i >= NE) return;
  int d = dst[i];
  int p = atomicAdd(&cursor[d], 1);
  csr_src[p] = src[i];
  csr_w[p] = w[i];
}

// ---------- plain bf16 GEMM: C = bf16(A(MxK) @ B(KxN)); B packed col-major [N][K] --
// v2: occupancy-tiled. block 256 / 4 waves; wave = 16x16 tile; block = 64 rows x 16 cols
// grid (M/64, N/16) = 2048 blocks -> 8 blocks/CU, 32 waves/CU (latency-hiding).
__global__ void gemm_plain_kernel(const u16* __restrict__ A, const u16* __restrict__ BT,
                                  u16* __restrict__ C, int M, int N, int K) {
  int wave = threadIdx.x >> 6, lane = threadIdx.x & 63;
  int r = lane & 15, kf = (lane >> 4) * 8;
  int row = blockIdx.x * 64 + wave * 16 + r;
  int col = blockIdx.y * 16 + r;
  f32x4 acc = {};
  for (int k0 = 0; k0 < K; k0 += 32) {
    int ka = k0 + kf;
    bf16x8 a = *(const bf16x8*)(A + (size_t)row * K + ka);
    bf16x8 b = *(const bf16x8*)(BT + (size_t)col * K + ka);
    acc = __builtin_amdgcn_mfma_f32_16x16x32_bf16(a, b, acc, 0, 0, 0);
  }
  int orow = blockIdx.x * 64 + wave * 16 + (lane >> 4) * 4;
#pragma unroll
  for (int q = 0; q < 4; ++q)
    C[(size_t)(orow + q) * N + blockIdx.y * 16 + r] = f2b(acc[q]);
}

// ---------- spmm (CSR): 4 nodes/block, 64 lanes/node, bf16x4 gather, 8-deep ----
__global__ void spmm_relu_kernel(const int* __restrict__ rowptr, const int* __restrict__ csr_src,
                                 const float* __restrict__ csr_w, const u16* __restrict__ h,
                                 u16* __restrict__ o) {
  int n = blockIdx.x * 4 + (threadIdx.x >> 6);
  int c = (threadIdx.x & 63) * 4;
  int e0 = rowptr[n], e1 = rowptr[n + 1];
  f32x4 acc = {};
  int i = e0;
  for (; i + 8 <= e1; i += 8) {
    float w[8];
    u16x4 v[8];
#pragma unroll
    for (int u = 0; u < 8; ++u) {
      w[u] = csr_w[i + u];
      v[u] = *(const u16x4*)(h + (size_t)csr_src[i + u] * 256 + c);
    }
#pragma unroll
    for (int u = 0; u < 8; ++u)
#pragma unroll
      for (int j = 0; j < 4; ++j) acc[j] = fmaf(w[u], b2f(v[u][j]), acc[j]);
  }
  for (; i < e1; ++i) {
    float w0 = csr_w[i];
    u16x4 v0 = *(const u16x4*)(h + (size_t)csr_src[i] * 256 + c);
#pragma unroll
    for (int j = 0; j < 4; ++j) acc[j] = fmaf(w0, b2f(v0[j]), acc[j]);
  }
  u16x4 vh;
#pragma unroll
  for (int j = 0; j < 4; ++j) vh[j] = f2b(fmaxf(acc[j], 0.f));
  *(u16x4*)(o + (size_t)n * 256 + c) = vh;
}

__global__ void spmm_out_kernel(const int* __restrict__ rowptr, const int* __restrict__ csr_src,
                                const float* __restrict__ csr_w, const u16* __restrict__ h,
                                float* __restrict__ mu, float* __restrict__ logvar,
                                float* __restrict__ z, u16* __restrict__ zb) {
  int n = blockIdx.x * 4 + (threadIdx.x >> 6);
  int c = (threadIdx.x & 63) * 4;
  int e0 = rowptr[n], e1 = rowptr[n + 1];
  f32x4 acc = {};
  int i = e0;
  for (; i + 8 <= e1; i += 8) {
    float w[8];
    u16x4 v[8];
#pragma unroll
    for (int u = 0; u < 8; ++u) {
      w[u] = csr_w[i + u];
      v[u] = *(const u16x4*)(h + (size_t)csr_src[i + u] * 256 + c);
    }
#pragma unroll
    for (int u = 0; u < 8; ++u)
#pragma unroll
      for (int j = 0; j < 4; ++j) acc[j] = fmaf(w[u], b2f(v[u][j]), acc[j]);
  }
  for (; i < e1; ++i) {
    float w0 = csr_w[i];
    u16x4 v0 = *(const u16x4*)(h + (size_t)csr_src[i] * 256 + c);
#pragma unroll
    for (int j = 0; j < 4; ++j) acc[j] = fmaf(w0, b2f(v0[j]), acc[j]);
  }
  if (c < 128) {
    *(f32x4*)(mu + (size_t)n * 128 + c) = acc;
    *(f32x4*)(z + (size_t)n * 128 + c) = acc;
    u16x4 vb;
#pragma unroll
    for (int j = 0; j < 4; ++j) vb[j] = f2b(acc[j]);
    *(u16x4*)(zb + (size_t)n * 128 + c) = vb;
  } else {
    *(f32x4*)(logvar + (size_t)n * 128 + (c - 128)) = acc;
  }
}

// ---------- adj = Z @ Z^T, Z [8192][128] bf16 ----------
// v3b (R7): A in registers, B in 32KB swizzled LDS -> 4 blocks/CU.
// block 256 / 4 waves; tile 128x128; wave = 32 rows x 128 cols; grid (64,64).
__global__ void zzt_kernel(const u16* __restrict__ Z, float* __restrict__ C) {
  __shared__ u16 lB[128 * 128];   // 32KB swizzled (rows = C cols)
  int t = threadIdx.x;
  int i0 = blockIdx.y * 128;
  int j0 = blockIdx.x * 128;
  const char* gB = (const char*)(Z + (size_t)j0 * 128);
#pragma unroll
  for (int cix = 0; cix < 8; ++cix) {
    int p = (cix * 256 + t) * 16;
    int row = p >> 8;
    int sw = (p & 255) ^ ((row & 15) << 4);
    bf16x8 vb = *(const bf16x8*)(gB + p);
    *(bf16x8*)((char*)lB + row * 256 + sw) = vb;
  }
  int wave = t >> 6, lane = t & 63;
  int lrow = lane & 31, hi = lane >> 5;
  const u16* aRow = Z + (size_t)(i0 + wave * 32 + lrow) * 128 + hi * 8;
  bf16x8 a[8];
#pragma unroll
  for (int k = 0; k < 8; ++k)
    a[k] = *(const bf16x8*)(aRow + k * 16);
  __syncthreads();
  f32x16 acc[4] = {};
#pragma unroll
  for (int ks = 0; ks < 8; ++ks) {
    int kb = ks * 32 + hi * 16;
#pragma unroll
    for (int tt = 0; tt < 4; ++tt) {
      int brow = tt * 32 + lrow;
      bf16x8 b = *(const bf16x8*)((const char*)lB + brow * 256 + (kb ^ ((brow & 15) << 4)));
      acc[tt] = __builtin_amdgcn_mfma_f32_32x32x16_bf16(a[ks], b, acc[tt], 0, 0, 0);
    }
  }
  int rb = wave * 32 + 4 * (lane >> 5);
  int col = lane & 31;
#pragma unroll
  for (int tt = 0; tt < 4; ++tt) {
#pragma unroll
    for (int reg = 0; reg < 16; ++reg) {
      int rr = rb + (reg & 3) + 8 * (reg >> 2);
      __builtin_nontemporal_store(acc[tt][reg],
          &C[(size_t)(i0 + rr) * NN + j0 + tt * 32 + col]);
    }
  }
}

extern "C" void kernel_launch(void* const* d_in, const int* in_sizes, int n_in,
                              void* d_out, int out_size, void* d_ws, size_t ws_size,
                              hipStream_t stream) {
  const float* x  = (const float*)d_in[0];
  const int*   ei = (const int*)d_in[1];
  const float* ew = (const float*)d_in[2];
  const float* W1 = (const float*)d_in[3];
  const float* W2 = (const float*)d_in[4];
  const float* W3 = (const float*)d_in[5];

  float* out    = (float*)d_out;
  float* adj    = out;                                   // [8192,8192]
  float* mu     = out + (size_t)NN * NN;                 // [8192,128]
  float* logv   = mu + (size_t)NN * 128;                 // [8192,128]
  float* z      = logv + (size_t)NN * 128;               // [8192,128]

  const int* srcp = ei;
  const int* dstp = ei + NE;

  char* ws = (char*)d_ws;
  size_t off = 0;
  auto alloc = [&](size_t b) -> void* {
    void* p = ws + off;
    off = (off + b + 255) & ~(size_t)255;
    return p;
  };
  u16* xb   = (u16*)alloc((size_t)NN * 512 * 2);
  u16* W1T  = (u16*)alloc(512 * 256 * 2);   // col-major [256][512]
  u16* W23T = (u16*)alloc(256 * 256 * 2);   // col-major [256][256]
  u16* h0b  = (u16*)alloc((size_t)NN * 256 * 2);   // bf16(x@W1)
  u16* h1b  = (u16*)alloc((size_t)NN * 256 * 2);   // bf16(relu(spmm))
  u16* H2b  = (u16*)alloc((size_t)NN * 256 * 2);   // bf16(h1@W23)
  u16* zb   = (u16*)alloc((size_t)NN * 128 * 2);
  int* deg      = (int*)alloc(NN * 4);
  int* rowptr   = (int*)alloc((NN + 1) * 4);
  int* cursor   = (int*)alloc(NN * 4);
  int* csr_src  = (int*)alloc((size_t)NE * 4);
  float* csr_w  = (float*)alloc((size_t)NE * 4);

  hipMemsetAsync(deg, 0, NN * 4, stream);

  // fused converts + degree histogram
  prep_kernel<<<4096 + 512 + 256 + 1024, 256, 0, stream>>>(x, W1, W2, W3, dstp, deg,
                                                           xb, W1T, W23T);

  // CSR build
  scan_kernel<<<1, 1024, 0, stream>>>(deg, rowptr, cursor);
  scatter_kernel<<<NE / 256, 256, 0, stream>>>(srcp, dstp, ew, cursor, csr_src, csr_w);

  // h0b = bf16(x @ W1)
  gemm_plain_kernel<<<dim3(NN / 64, 256 / 16), 256, 0, stream>>>(xb, W1T, h0b,
                                                                 NN, 256, 512);
  // h1b = bf16(relu(spmm(h0b)))
  spmm_relu_kernel<<<NN / 4, 256, 0, stream>>>(rowptr, csr_src, csr_w, h0b, h1b);
  // H2b = bf16(h1 @ [W2|W3])
  gemm_plain_kernel<<<dim3(NN / 64, 256 / 16), 256, 0, stream>>>(h1b, W23T, H2b,
                                                                 NN, 256, 256);
  // mu/logvar = spmm(H2b); z = mu; zb = bf16(mu)
  spmm_out_kernel<<<NN / 4, 256, 0, stream>>>(rowptr, csr_src, csr_w, H2b, mu, logv, z, zb);
  // adj = z @ z^T  (A-in-reg, B-in-LDS, 4 blocks/CU)
  zzt_kernel<<<dim3(NN / 128, NN / 128), 256, 0, stream>>>(zb, adj);
}

// Round 13
// 167.218 us; speedup vs baseline: 1.0923x; 1.0923x over previous
//
#include <hip/hip_runtime.h>
#include <hip/hip_bf16.h>

#define NN 8192
#define NE 262144

typedef __attribute__((ext_vector_type(8))) short bf16x8;
typedef __attribute__((ext_vector_type(4))) float f32x4;
typedef __attribute__((ext_vector_type(16))) float f32x16;
typedef unsigned short u16;
typedef __attribute__((ext_vector_type(4))) u16 u16x4;

__device__ inline u16 f2b(float f) {
  unsigned u = __float_as_uint(f);
  unsigned r = u + 0x7FFF + ((u >> 16) & 1);   // RNE to bf16
  return (u16)(r >> 16);
}
__device__ inline float b2f(u16 b) {
  return __uint_as_float(((unsigned)b) << 16);
}

// ---------- fused prep: x->bf16 (4096 blks) | W1^T (512) | W23^T (256) | hist (1024) --
__global__ void prep_kernel(const float* __restrict__ x, const float* __restrict__ W1,
                            const float* __restrict__ W2, const float* __restrict__ W3,
                            const int* __restrict__ dst, int* __restrict__ deg,
                            u16* __restrict__ xb, u16* __restrict__ W1T,
                            u16* __restrict__ W23T) {
  int b = blockIdx.x;
  if (b < 4096) {
    int i = (b * 256 + threadIdx.x) * 4;
    f32x4 v = *(const f32x4*)(x + i);
    u16x4 o;
#pragma unroll
    for (int j = 0; j < 4; ++j) o[j] = f2b(v[j]);
    *(u16x4*)(xb + i) = o;
  } else if (b < 4096 + 512) {
    int i = (b - 4096) * 256 + threadIdx.x;   // 512*256 elems
    int k = i >> 8, n = i & 255;
    W1T[(size_t)n * 512 + k] = f2b(W1[i]);
  } else if (b < 4096 + 512 + 256) {
    int i = (b - 4608) * 256 + threadIdx.x;   // 65536 elems
    int k = i >> 8, j = i & 255;
    float v = (j < 128) ? W2[(k << 7) + j] : W3[(k << 7) + (j - 128)];
    W23T[(size_t)j * 256 + k] = f2b(v);
  } else {
    int i = (b - 4864) * 256 + threadIdx.x;   // NE elems
    if (i < NE) atomicAdd(&deg[dst[i]], 1);
  }
}

// ---------- CSR build ----------
__global__ void scan_kernel(const int* __restrict__ deg, int* __restrict__ rowptr,
                            int* __restrict__ cursor) {
  __shared__ int sums[1024];
  int t = threadIdx.x;
  int loc[8];
  int s = 0;
#pragma unroll
  for (int j = 0; j < 8; ++j) { s += deg[t * 8 + j]; loc[j] = s; }
  sums[t] = s;
  __syncthreads();
  for (int off = 1; off < 1024; off <<= 1) {
    int v = (t >= off) ? sums[t - off] : 0;
    __syncthreads();
    sums[t] += v;
    __syncthreads();
  }
  int base = (t > 0) ? sums[t - 1] : 0;
  if (t == 0) rowptr[0] = 0;
#pragma unroll
  for (int j = 0; j < 8; ++j) {
    rowptr[t * 8 + j + 1] = base + loc[j];
    cursor[t * 8 + j] = base + (j ? loc[j - 1] : 0);
  }
}

__global__ void scatter_kernel(const int* __restrict__ src, const int* __restrict__ dst,
                               const float* __restrict__ w, int* cursor,
                               int* __restrict__ csr_src, float* __restrict__ csr_w) {
  int i = blockIdx.x * blockDim.x + threadIdx.x;
  if (i >= NE) return;
  int d = dst[i];
  int p = atomicAdd(&cursor[d], 1);
  csr_src[p] = src[i];
  csr_w[p] = w[i];
}

// ---------- plain bf16 GEMM: C = bf16(A(MxK) @ B(KxN)); B packed col-major [N][K] --
// v3: R11 wave-tile (16 rows x 64 cols, 4 acc chains) but 1-wave blocks:
// grid (M/16, N/64) = 2048 blocks -> ~4x wave concurrency vs R11, same A:B ratio.
__global__ void gemm_plain_kernel(const u16* __restrict__ A, const u16* __restrict__ BT,
                                  u16* __restrict__ C, int M, int N, int K) {
  int lane = threadIdx.x;
  int r = lane & 15, kf = (lane >> 4) * 8;
  int row = blockIdx.x * 16 + r;
  int col0 = blockIdx.y * 64;
  f32x4 acc[4] = {};
  for (int k0 = 0; k0 < K; k0 += 32) {
    int ka = k0 + kf;
    bf16x8 a = *(const bf16x8*)(A + (size_t)row * K + ka);
#pragma unroll
    for (int t = 0; t < 4; ++t) {
      bf16x8 b = *(const bf16x8*)(BT + (size_t)(col0 + t * 16 + r) * K + ka);
      acc[t] = __builtin_amdgcn_mfma_f32_16x16x32_bf16(a, b, acc[t], 0, 0, 0);
    }
  }
  int orow = blockIdx.x * 16 + (lane >> 4) * 4;
#pragma unroll
  for (int t = 0; t < 4; ++t)
#pragma unroll
    for (int q = 0; q < 4; ++q)
      C[(size_t)(orow + q) * N + col0 + t * 16 + r] = f2b(acc[t][q]);
}

// ---------- spmm (CSR): 4 nodes/block, 64 lanes/node, bf16x4 gather, 4-deep ----
__global__ void spmm_relu_kernel(const int* __restrict__ rowptr, const int* __restrict__ csr_src,
                                 const float* __restrict__ csr_w, const u16* __restrict__ h,
                                 u16* __restrict__ o) {
  int n = blockIdx.x * 4 + (threadIdx.x >> 6);
  int c = (threadIdx.x & 63) * 4;
  int e0 = rowptr[n], e1 = rowptr[n + 1];
  f32x4 acc = {};
  int i = e0;
  for (; i + 4 <= e1; i += 4) {
    int s0 = csr_src[i], s1 = csr_src[i + 1], s2 = csr_src[i + 2], s3 = csr_src[i + 3];
    float w0 = csr_w[i], w1 = csr_w[i + 1], w2 = csr_w[i + 2], w3 = csr_w[i + 3];
    u16x4 v0 = *(const u16x4*)(h + (size_t)s0 * 256 + c);
    u16x4 v1 = *(const u16x4*)(h + (size_t)s1 * 256 + c);
    u16x4 v2 = *(const u16x4*)(h + (size_t)s2 * 256 + c);
    u16x4 v3 = *(const u16x4*)(h + (size_t)s3 * 256 + c);
#pragma unroll
    for (int j = 0; j < 4; ++j) {
      acc[j] = fmaf(w0, b2f(v0[j]), acc[j]);
      acc[j] = fmaf(w1, b2f(v1[j]), acc[j]);
      acc[j] = fmaf(w2, b2f(v2[j]), acc[j]);
      acc[j] = fmaf(w3, b2f(v3[j]), acc[j]);
    }
  }
  for (; i < e1; ++i) {
    float w0 = csr_w[i];
    u16x4 v0 = *(const u16x4*)(h + (size_t)csr_src[i] * 256 + c);
#pragma unroll
    for (int j = 0; j < 4; ++j) acc[j] = fmaf(w0, b2f(v0[j]), acc[j]);
  }
  u16x4 vh;
#pragma unroll
  for (int j = 0; j < 4; ++j) vh[j] = f2b(fmaxf(acc[j], 0.f));
  *(u16x4*)(o + (size_t)n * 256 + c) = vh;
}

__global__ void spmm_out_kernel(const int* __restrict__ rowptr, const int* __restrict__ csr_src,
                                const float* __restrict__ csr_w, const u16* __restrict__ h,
                                float* __restrict__ mu, float* __restrict__ logvar,
                                float* __restrict__ z, u16* __restrict__ zb) {
  int n = blockIdx.x * 4 + (threadIdx.x >> 6);
  int c = (threadIdx.x & 63) * 4;
  int e0 = rowptr[n], e1 = rowptr[n + 1];
  f32x4 acc = {};
  int i = e0;
  for (; i + 4 <= e1; i += 4) {
    int s0 = csr_src[i], s1 = csr_src[i + 1], s2 = csr_src[i + 2], s3 = csr_src[i + 3];
    float w0 = csr_w[i], w1 = csr_w[i + 1], w2 = csr_w[i + 2], w3 = csr_w[i + 3];
    u16x4 v0 = *(const u16x4*)(h + (size_t)s0 * 256 + c);
    u16x4 v1 = *(const u16x4*)(h + (size_t)s1 * 256 + c);
    u16x4 v2 = *(const u16x4*)(h + (size_t)s2 * 256 + c);
    u16x4 v3 = *(const u16x4*)(h + (size_t)s3 * 256 + c);
#pragma unroll
    for (int j = 0; j < 4; ++j) {
      acc[j] = fmaf(w0, b2f(v0[j]), acc[j]);
      acc[j] = fmaf(w1, b2f(v1[j]), acc[j]);
      acc[j] = fmaf(w2, b2f(v2[j]), acc[j]);
      acc[j] = fmaf(w3, b2f(v3[j]), acc[j]);
    }
  }
  for (; i < e1; ++i) {
    float w0 = csr_w[i];
    u16x4 v0 = *(const u16x4*)(h + (size_t)csr_src[i] * 256 + c);
#pragma unroll
    for (int j = 0; j < 4; ++j) acc[j] = fmaf(w0, b2f(v0[j]), acc[j]);
  }
  if (c < 128) {
    *(f32x4*)(mu + (size_t)n * 128 + c) = acc;
    *(f32x4*)(z + (size_t)n * 128 + c) = acc;
    u16x4 vb;
#pragma unroll
    for (int j = 0; j < 4; ++j) vb[j] = f2b(acc[j]);
    *(u16x4*)(zb + (size_t)n * 128 + c) = vb;
  } else {
    *(f32x4*)(logvar + (size_t)n * 128 + (c - 128)) = acc;
  }
}

// ---------- adj = Z @ Z^T, Z [8192][128] bf16 ----------
// v3b (R7): A in registers, B in 32KB swizzled LDS -> 4 blocks/CU.
// block 256 / 4 waves; tile 128x128; wave = 32 rows x 128 cols; grid (64,64).
__global__ void zzt_kernel(const u16* __restrict__ Z, float* __restrict__ C) {
  __shared__ u16 lB[128 * 128];   // 32KB swizzled (rows = C cols)
  int t = threadIdx.x;
  int i0 = blockIdx.y * 128;
  int j0 = blockIdx.x * 128;
  const char* gB = (const char*)(Z + (size_t)j0 * 128);
#pragma unroll
  for (int cix = 0; cix < 8; ++cix) {
    int p = (cix * 256 + t) * 16;
    int row = p >> 8;
    int sw = (p & 255) ^ ((row & 15) << 4);
    bf16x8 vb = *(const bf16x8*)(gB + p);
    *(bf16x8*)((char*)lB + row * 256 + sw) = vb;
  }
  int wave = t >> 6, lane = t & 63;
  int lrow = lane & 31, hi = lane >> 5;
  const u16* aRow = Z + (size_t)(i0 + wave * 32 + lrow) * 128 + hi * 8;
  bf16x8 a[8];
#pragma unroll
  for (int k = 0; k < 8; ++k)
    a[k] = *(const bf16x8*)(aRow + k * 16);
  __syncthreads();
  f32x16 acc[4] = {};
#pragma unroll
  for (int ks = 0; ks < 8; ++ks) {
    int kb = ks * 32 + hi * 16;
#pragma unroll
    for (int tt = 0; tt < 4; ++tt) {
      int brow = tt * 32 + lrow;
      bf16x8 b = *(const bf16x8*)((const char*)lB + brow * 256 + (kb ^ ((brow & 15) << 4)));
      acc[tt] = __builtin_amdgcn_mfma_f32_32x32x16_bf16(a[ks], b, acc[tt], 0, 0, 0);
    }
  }
  int rb = wave * 32 + 4 * (lane >> 5);
  int col = lane & 31;
#pragma unroll
  for (int tt = 0; tt < 4; ++tt) {
#pragma unroll
    for (int reg = 0; reg < 16; ++reg) {
      int rr = rb + (reg & 3) + 8 * (reg >> 2);
      __builtin_nontemporal_store(acc[tt][reg],
          &C[(size_t)(i0 + rr) * NN + j0 + tt * 32 + col]);
    }
  }
}

extern "C" void kernel_launch(void* const* d_in, const int* in_sizes, int n_in,
                              void* d_out, int out_size, void* d_ws, size_t ws_size,
                              hipStream_t stream) {
  const float* x  = (const float*)d_in[0];
  const int*   ei = (const int*)d_in[1];
  const float* ew = (const float*)d_in[2];
  const float* W1 = (const float*)d_in[3];
  const float* W2 = (const float*)d_in[4];
  const float* W3 = (const float*)d_in[5];

  float* out    = (float*)d_out;
  float* adj    = out;                                   // [8192,8192]
  float* mu     = out + (size_t)NN * NN;                 // [8192,128]
  float* logv   = mu + (size_t)NN * 128;                 // [8192,128]
  float* z      = logv + (size_t)NN * 128;               // [8192,128]

  const int* srcp = ei;
  const int* dstp = ei + NE;

  char* ws = (char*)d_ws;
  size_t off = 0;
  auto alloc = [&](size_t b) -> void* {
    void* p = ws + off;
    off = (off + b + 255) & ~(size_t)255;
    return p;
  };
  u16* xb   = (u16*)alloc((size_t)NN * 512 * 2);
  u16* W1T  = (u16*)alloc(512 * 256 * 2);   // col-major [256][512]
  u16* W23T = (u16*)alloc(256 * 256 * 2);   // col-major [256][256]
  u16* h0b  = (u16*)alloc((size_t)NN * 256 * 2);   // bf16(x@W1)
  u16* h1b  = (u16*)alloc((size_t)NN * 256 * 2);   // bf16(relu(spmm))
  u16* H2b  = (u16*)alloc((size_t)NN * 256 * 2);   // bf16(h1@W23)
  u16* zb   = (u16*)alloc((size_t)NN * 128 * 2);
  int* deg      = (int*)alloc(NN * 4);
  int* rowptr   = (int*)alloc((NN + 1) * 4);
  int* cursor   = (int*)alloc(NN * 4);
  int* csr_src  = (int*)alloc((size_t)NE * 4);
  float* csr_w  = (float*)alloc((size_t)NE * 4);

  hipMemsetAsync(deg, 0, NN * 4, stream);

  // fused converts + degree histogram
  prep_kernel<<<4096 + 512 + 256 + 1024, 256, 0, stream>>>(x, W1, W2, W3, dstp, deg,
                                                           xb, W1T, W23T);

  // CSR build
  scan_kernel<<<1, 1024, 0, stream>>>(deg, rowptr, cursor);
  scatter_kernel<<<NE / 256, 256, 0, stream>>>(srcp, dstp, ew, cursor, csr_src, csr_w);

  // h0b = bf16(x @ W1)  -- 1-wave blocks, grid (M/16, N/64)
  gemm_plain_kernel<<<dim3(NN / 16, 256 / 64), 64, 0, stream>>>(xb, W1T, h0b,
                                                                NN, 256, 512);
  // h1b = bf16(relu(spmm(h0b)))
  spmm_relu_kernel<<<NN / 4, 256, 0, stream>>>(rowptr, csr_src, csr_w, h0b, h1b);
  // H2b = bf16(h1 @ [W2|W3])
  gemm_plain_kernel<<<dim3(NN / 16, 256 / 64), 64, 0, stream>>>(h1b, W23T, H2b,
                                                                NN, 256, 256);
  // mu/logvar = spmm(H2b); z = mu; zb = bf16(mu)
  spmm_out_kernel<<<NN / 4, 256, 0, stream>>>(rowptr, csr_src, csr_w, H2b, mu, logv, z, zb);
  // adj = z @ z^T  (A-in-reg, B-in-LDS, 4 blocks/CU)
  zzt_kernel<<<dim3(NN / 128, NN / 128), 256, 0, stream>>>(zb, adj);
}